// Round 1
// baseline (8119.758 us; speedup 1.0000x reference)
//
#include <hip/hip_runtime.h>
#include <math.h>

#define N_NODES 100000
#define N_EDGES 3200000

// ---------------- degree count: deg[col[e]] += 1 ----------------
__global__ void deg_count_kernel(const int* __restrict__ col, float* __restrict__ deg) {
    int e = blockIdx.x * 256 + threadIdx.x;
    if (e < N_EDGES) atomicAdd(&deg[col[e]], 1.0f);
}

// ---- deg -> rsqrt(deg+1) in place; also reduce sum(labels) -> npos ----
__global__ void deg_finish_kernel(float* __restrict__ deg, const float* __restrict__ labels,
                                  float* __restrict__ npos) {
    int i = blockIdx.x * 256 + threadIdx.x;
    float lab = 0.0f;
    if (i < N_NODES) {
        deg[i] = rsqrtf(deg[i] + 1.0f);
        lab = labels[i];
    }
    __shared__ float red[256];
    red[threadIdx.x] = lab;
    __syncthreads();
    for (int s = 128; s > 0; s >>= 1) {
        if (threadIdx.x < s) red[threadIdx.x] += red[threadIdx.x + s];
        __syncthreads();
    }
    if (threadIdx.x == 0) atomicAdd(npos, red[0]);
}

// ---------------- norm[e] = isq[row[e]] * isq[col[e]] ----------------
__global__ void norm_kernel(const int* __restrict__ row, const int* __restrict__ col,
                            const float* __restrict__ isq, float* __restrict__ norm) {
    int e = blockIdx.x * 256 + threadIdx.x;
    if (e < N_EDGES) norm[e] = isq[row[e]] * isq[col[e]];
}

// ------- m = in @ W ; agg = m * isq^2 (self-loop init). 4 nodes/block -------
template <int K>
__global__ void linear_selfloop_kernel(const float* __restrict__ in, const float* __restrict__ W,
                                       const float* __restrict__ isq, float* __restrict__ m,
                                       float* __restrict__ agg) {
    __shared__ float sW[K * 64];
    for (int t = threadIdx.x; t < K * 64; t += 256) sW[t] = W[t];
    __syncthreads();
    int node = blockIdx.x * 4 + (threadIdx.x >> 6);
    int f = threadIdx.x & 63;
    if (node >= N_NODES) return;
    const float* inr = in + (size_t)node * K;
    float acc = 0.0f;
#pragma unroll
    for (int k = 0; k < K; ++k) acc = fmaf(inr[k], sW[k * 64 + f], acc);
    m[(size_t)node * 64 + f] = acc;
    float s = isq[node];
    agg[(size_t)node * 64 + f] = acc * s * s;
}

// ------- scatter: agg[col[e]][:] += m[row[e]][:] * norm[e]; 16 thr/edge -------
__global__ void scatter_kernel(const int* __restrict__ row, const int* __restrict__ col,
                               const float* __restrict__ norm, const float* __restrict__ m,
                               float* __restrict__ agg) {
    int tid = blockIdx.x * 256 + threadIdx.x;
    int e = tid >> 4;
    int q = tid & 15;
    if (e >= N_EDGES) return;
    int r = row[e];
    int c = col[e];
    float nv = norm[e];
    const float4 mv = *(const float4*)(m + (size_t)r * 64 + q * 4);
    float* a = agg + (size_t)c * 64 + q * 4;
    atomicAdd(a + 0, mv.x * nv);
    atomicAdd(a + 1, mv.y * nv);
    atomicAdd(a + 2, mv.z * nv);
    atomicAdd(a + 3, mv.w * nv);
}

// ---------------- h = relu(agg + b) ----------------
__global__ void bias_relu_kernel(const float* __restrict__ agg, const float* __restrict__ b,
                                 float* __restrict__ h) {
    int i = blockIdx.x * 256 + threadIdx.x;
    if (i < N_NODES * 64) {
        float v = agg[i] + b[i & 63];
        h[i] = v > 0.0f ? v : 0.0f;
    }
}

// ---- head: relu(h@Wl1+bl1)@Wl2+bl2 -> sigmoid -> p; weighted BCE -> loss ----
__global__ void head_kernel(const float* __restrict__ h, const float* __restrict__ Wl1,
                            const float* __restrict__ bl1, const float* __restrict__ Wl2,
                            const float* __restrict__ bl2, const float* __restrict__ labels,
                            const float* __restrict__ npos, float* __restrict__ out) {
    __shared__ float sW1[64 * 8];
    __shared__ float sb1[8];
    __shared__ float sW2[8];
    for (int t = threadIdx.x; t < 512; t += 256) sW1[t] = Wl1[t];
    if (threadIdx.x < 8) {
        sb1[threadIdx.x] = bl1[threadIdx.x];
        sW2[threadIdx.x] = Wl2[threadIdx.x];
    }
    __syncthreads();
    int i = blockIdx.x * 256 + threadIdx.x;
    float contrib = 0.0f;
    if (i < N_NODES) {
        const float* hr = h + (size_t)i * 64;
        float a[8];
#pragma unroll
        for (int j = 0; j < 8; ++j) a[j] = sb1[j];
        for (int k = 0; k < 64; ++k) {
            float hv = hr[k];
#pragma unroll
            for (int j = 0; j < 8; ++j) a[j] = fmaf(hv, sW1[k * 8 + j], a[j]);
        }
        float z = bl2[0];
#pragma unroll
        for (int j = 0; j < 8; ++j) {
            float r = a[j] > 0.0f ? a[j] : 0.0f;
            z = fmaf(r, sW2[j], z);
        }
        float p = 1.0f / (1.0f + expf(-z));
        out[1 + i] = p;
        float y = labels[i];
        float np = *npos;
        float fn = (float)N_NODES;
        float wpos = fn / (2.0f * np);
        float wneg = fn / (2.0f * (fn - np));
        float w = y * wpos + (1.0f - y) * wneg;
        // log_sigmoid(z) = min(z,0) - log1p(exp(-|z|))
        float lse = log1pf(expf(-fabsf(z)));
        float ls_pos = fminf(z, 0.0f) - lse;
        float ls_neg = fminf(-z, 0.0f) - lse;
        float bce = -(y * ls_pos + (1.0f - y) * ls_neg);
        contrib = w * bce / fn;
    }
    __shared__ float red[256];
    red[threadIdx.x] = contrib;
    __syncthreads();
    for (int s = 128; s > 0; s >>= 1) {
        if (threadIdx.x < s) red[threadIdx.x] += red[threadIdx.x + s];
        __syncthreads();
    }
    if (threadIdx.x == 0) atomicAdd(out, red[0]);
}

extern "C" void kernel_launch(void* const* d_in, const int* in_sizes, int n_in,
                              void* d_out, int out_size, void* d_ws, size_t ws_size,
                              hipStream_t stream) {
    const float* x      = (const float*)d_in[0];
    const int*   ei     = (const int*)d_in[1];
    const float* labels = (const float*)d_in[2];
    const float* W1  = (const float*)d_in[3];
    const float* b1  = (const float*)d_in[4];
    const float* W2  = (const float*)d_in[5];
    const float* b2  = (const float*)d_in[6];
    const float* W3  = (const float*)d_in[7];
    const float* b3  = (const float*)d_in[8];
    const float* Wl1 = (const float*)d_in[9];
    const float* bl1 = (const float*)d_in[10];
    const float* Wl2 = (const float*)d_in[11];
    const float* bl2 = (const float*)d_in[12];

    const int* row = ei;            // edge_index[0]
    const int* col = ei + N_EDGES;  // edge_index[1]

    float* out = (float*)d_out;

    // workspace layout (floats)
    float* deg  = (float*)d_ws;                 // N (becomes rsqrt(deg+1))
    float* npos = deg + N_NODES;                // 1 (+ pad to 256)
    float* norm = npos + 256;                   // E
    float* bufM = norm + N_EDGES;               // N*64
    float* bufC = bufM + (size_t)N_NODES * 64;  // N*64
    float* bufA = bufC + (size_t)N_NODES * 64;  // N*64

    hipMemsetAsync(deg, 0, N_NODES * sizeof(float), stream);
    hipMemsetAsync(npos, 0, sizeof(float), stream);
    hipMemsetAsync(out, 0, sizeof(float), stream);

    const int EB = (N_EDGES + 255) / 256;       // 12500
    const int NB = (N_NODES + 255) / 256;       // 391
    const int LB = (N_NODES + 3) / 4;           // 25000
    const int SB = (N_EDGES * 16) / 256;        // 200000
    const int RB = (N_NODES * 64 + 255) / 256;  // 25000

    deg_count_kernel<<<EB, 256, 0, stream>>>(col, deg);
    deg_finish_kernel<<<NB, 256, 0, stream>>>(deg, labels, npos);
    norm_kernel<<<EB, 256, 0, stream>>>(row, col, deg, norm);

    // layer 1 (K=32)
    linear_selfloop_kernel<32><<<LB, 256, 0, stream>>>(x, W1, deg, bufM, bufC);
    scatter_kernel<<<SB, 256, 0, stream>>>(row, col, norm, bufM, bufC);
    bias_relu_kernel<<<RB, 256, 0, stream>>>(bufC, b1, bufA);

    // layer 2 (K=64)
    linear_selfloop_kernel<64><<<LB, 256, 0, stream>>>(bufA, W2, deg, bufM, bufC);
    scatter_kernel<<<SB, 256, 0, stream>>>(row, col, norm, bufM, bufC);
    bias_relu_kernel<<<RB, 256, 0, stream>>>(bufC, b2, bufA);

    // layer 3 (K=64)
    linear_selfloop_kernel<64><<<LB, 256, 0, stream>>>(bufA, W3, deg, bufM, bufC);
    scatter_kernel<<<SB, 256, 0, stream>>>(row, col, norm, bufM, bufC);
    bias_relu_kernel<<<RB, 256, 0, stream>>>(bufC, b3, bufA);

    head_kernel<<<NB, 256, 0, stream>>>(bufA, Wl1, bl1, Wl2, bl2, labels, npos, out);
}

// Round 2
// 865.329 us; speedup vs baseline: 9.3834x; 9.3834x over previous
//
#include <hip/hip_runtime.h>
#include <math.h>

#define N_NODES 100000
#define N_EDGES 3200000

// ---------------- degree histogram: degi[col[e]] += 1 ----------------
__global__ void count_kernel(const int* __restrict__ col, int* __restrict__ degi) {
    int e = blockIdx.x * 256 + threadIdx.x;
    if (e < N_EDGES) atomicAdd(&degi[col[e]], 1);
}

// ---------------- block-level exclusive scan over degi[0..N] ----------------
__global__ void scan_blocks_kernel(const int* __restrict__ degi, int* __restrict__ starts,
                                   int* __restrict__ blockSums) {
    __shared__ int tmp[256];
    int i = blockIdx.x * 256 + threadIdx.x;
    int v = (i <= N_NODES) ? degi[i] : 0;
    tmp[threadIdx.x] = v;
    __syncthreads();
    for (int off = 1; off < 256; off <<= 1) {
        int t = (threadIdx.x >= off) ? tmp[threadIdx.x - off] : 0;
        __syncthreads();
        if (threadIdx.x >= off) tmp[threadIdx.x] += t;
        __syncthreads();
    }
    if (i <= N_NODES) starts[i] = tmp[threadIdx.x] - v;  // exclusive (partial)
    if (threadIdx.x == 255) blockSums[blockIdx.x] = tmp[255];
}

// ---------------- scan of per-block sums (single block, 512 wide) ----------------
__global__ void scan_sums_kernel(int* __restrict__ blockSums, int* __restrict__ blockOffs,
                                 int nb) {
    __shared__ int tmp[512];
    int tx = threadIdx.x;
    int v = (tx < nb) ? blockSums[tx] : 0;
    tmp[tx] = v;
    __syncthreads();
    for (int off = 1; off < 512; off <<= 1) {
        int t = (tx >= off) ? tmp[tx - off] : 0;
        __syncthreads();
        if (tx >= off) tmp[tx] += t;
        __syncthreads();
    }
    if (tx < nb) blockOffs[tx] = tmp[tx] - v;  // exclusive
}

// ---- finalize: starts += blockOff; cursor = starts; isq = rsqrt(deg+1); npos ----
__global__ void finalize_kernel(int* __restrict__ starts, const int* __restrict__ blockOffs,
                                const int* __restrict__ degi, int* __restrict__ cursor,
                                float* __restrict__ isq, const float* __restrict__ labels,
                                float* __restrict__ npos) {
    int i = blockIdx.x * 256 + threadIdx.x;
    float lab = 0.0f;
    if (i <= N_NODES) {
        int s = starts[i] + blockOffs[blockIdx.x];
        starts[i] = s;
        if (i < N_NODES) {
            cursor[i] = s;
            isq[i] = rsqrtf((float)degi[i] + 1.0f);
            lab = labels[i];
        }
    }
    __shared__ float red[256];
    red[threadIdx.x] = lab;
    __syncthreads();
    for (int s = 128; s > 0; s >>= 1) {
        if (threadIdx.x < s) red[threadIdx.x] += red[threadIdx.x + s];
        __syncthreads();
    }
    if (threadIdx.x == 0) atomicAdd(npos, red[0]);
}

// ---------------- CSR fill: edges[pos] = {row, isq[row]*isq[col]} ----------------
__global__ void fill_kernel(const int* __restrict__ row, const int* __restrict__ col,
                            const float* __restrict__ isq, int* __restrict__ cursor,
                            int2* __restrict__ edges) {
    int e = blockIdx.x * 256 + threadIdx.x;
    if (e >= N_EDGES) return;
    int r = row[e];
    int c = col[e];
    int pos = atomicAdd(&cursor[c], 1);
    float nv = isq[r] * isq[c];
    edges[pos] = make_int2(r, __float_as_int(nv));
}

// ---------------- m = in @ W ; weights staged in LDS; 4 nodes/block ----------------
template <int K>
__global__ void linear_kernel(const float* __restrict__ in, const float* __restrict__ W,
                              float* __restrict__ m) {
    __shared__ float sW[K * 64];
    for (int t = threadIdx.x; t < K * 64; t += 256) sW[t] = W[t];
    __syncthreads();
    int node = blockIdx.x * 4 + (threadIdx.x >> 6);
    int f = threadIdx.x & 63;
    if (node >= N_NODES) return;
    const float* inr = in + (size_t)node * K;
    float acc = 0.0f;
#pragma unroll
    for (int k = 0; k < K; ++k) acc = fmaf(inr[k], sW[k * 64 + f], acc);
    m[(size_t)node * 64 + f] = acc;
}

// ---- gather: h[i] = relu( sum_{e: col=i} m[row_e]*norm_e + m[i]*isq[i]^2 + b ) ----
__global__ void gather_kernel(const int* __restrict__ starts, const int2* __restrict__ edges,
                              const float* __restrict__ m, const float* __restrict__ isq,
                              const float* __restrict__ bias, float* __restrict__ h) {
    int node = blockIdx.x * 4 + (threadIdx.x >> 6);
    int lane = threadIdx.x & 63;
    if (node >= N_NODES) return;
    int s = starts[node];
    int e = starts[node + 1];
    float si = isq[node];
    float acc = m[(size_t)node * 64 + lane] * si * si;  // self-loop term
    float acc2 = 0.0f;
    while (s < e) {
        int cnt = e - s;
        if (cnt > 64) cnt = 64;
        int2 med = (lane < cnt) ? edges[s + lane] : make_int2(0, 0);
        int j = 0;
        for (; j + 2 <= cnt; j += 2) {
            int r0 = __shfl(med.x, j);
            int r1 = __shfl(med.x, j + 1);
            float n0 = __int_as_float(__shfl(med.y, j));
            float n1 = __int_as_float(__shfl(med.y, j + 1));
            float v0 = m[(size_t)r0 * 64 + lane];
            float v1 = m[(size_t)r1 * 64 + lane];
            acc = fmaf(v0, n0, acc);
            acc2 = fmaf(v1, n1, acc2);
        }
        if (j < cnt) {
            int r0 = __shfl(med.x, j);
            float n0 = __int_as_float(__shfl(med.y, j));
            acc = fmaf(m[(size_t)r0 * 64 + lane], n0, acc);
        }
        s += cnt;
    }
    float v = acc + acc2 + bias[lane];
    h[(size_t)node * 64 + lane] = v > 0.0f ? v : 0.0f;
}

// ---- head: relu(h@Wl1+bl1)@Wl2+bl2 -> sigmoid -> p; weighted BCE -> loss ----
__global__ void head_kernel(const float* __restrict__ h, const float* __restrict__ Wl1,
                            const float* __restrict__ bl1, const float* __restrict__ Wl2,
                            const float* __restrict__ bl2, const float* __restrict__ labels,
                            const float* __restrict__ npos, float* __restrict__ out) {
    __shared__ float sW1[64 * 8];
    __shared__ float sb1[8];
    __shared__ float sW2[8];
    for (int t = threadIdx.x; t < 512; t += 256) sW1[t] = Wl1[t];
    if (threadIdx.x < 8) {
        sb1[threadIdx.x] = bl1[threadIdx.x];
        sW2[threadIdx.x] = Wl2[threadIdx.x];
    }
    __syncthreads();
    int i = blockIdx.x * 256 + threadIdx.x;
    float contrib = 0.0f;
    if (i < N_NODES) {
        const float* hr = h + (size_t)i * 64;
        float a[8];
#pragma unroll
        for (int j = 0; j < 8; ++j) a[j] = sb1[j];
        for (int k = 0; k < 64; ++k) {
            float hv = hr[k];
#pragma unroll
            for (int j = 0; j < 8; ++j) a[j] = fmaf(hv, sW1[k * 8 + j], a[j]);
        }
        float z = bl2[0];
#pragma unroll
        for (int j = 0; j < 8; ++j) {
            float r = a[j] > 0.0f ? a[j] : 0.0f;
            z = fmaf(r, sW2[j], z);
        }
        float p = 1.0f / (1.0f + expf(-z));
        out[1 + i] = p;
        float y = labels[i];
        float np = *npos;
        float fn = (float)N_NODES;
        float wpos = fn / (2.0f * np);
        float wneg = fn / (2.0f * (fn - np));
        float w = y * wpos + (1.0f - y) * wneg;
        float lse = log1pf(expf(-fabsf(z)));
        float ls_pos = fminf(z, 0.0f) - lse;
        float ls_neg = fminf(-z, 0.0f) - lse;
        float bce = -(y * ls_pos + (1.0f - y) * ls_neg);
        contrib = w * bce / fn;
    }
    __shared__ float red[256];
    red[threadIdx.x] = contrib;
    __syncthreads();
    for (int s = 128; s > 0; s >>= 1) {
        if (threadIdx.x < s) red[threadIdx.x] += red[threadIdx.x + s];
        __syncthreads();
    }
    if (threadIdx.x == 0) atomicAdd(out, red[0]);
}

extern "C" void kernel_launch(void* const* d_in, const int* in_sizes, int n_in,
                              void* d_out, int out_size, void* d_ws, size_t ws_size,
                              hipStream_t stream) {
    const float* x      = (const float*)d_in[0];
    const int*   ei     = (const int*)d_in[1];
    const float* labels = (const float*)d_in[2];
    const float* W1  = (const float*)d_in[3];
    const float* b1  = (const float*)d_in[4];
    const float* W2  = (const float*)d_in[5];
    const float* b2  = (const float*)d_in[6];
    const float* W3  = (const float*)d_in[7];
    const float* b3  = (const float*)d_in[8];
    const float* Wl1 = (const float*)d_in[9];
    const float* bl1 = (const float*)d_in[10];
    const float* Wl2 = (const float*)d_in[11];
    const float* bl2 = (const float*)d_in[12];

    const int* row = ei;            // edge_index[0]
    const int* col = ei + N_EDGES;  // edge_index[1]
    float* out = (float*)d_out;

    // ---- workspace layout ----
    char* w = (char*)d_ws;
    int2*  edges = (int2*)w;                               // E * 8B
    float* bufM  = (float*)(w + (size_t)N_EDGES * 8);      // N*64 f32
    float* bufA  = bufM + (size_t)N_NODES * 64;            // N*64 f32
    int*   degi  = (int*)(bufA + (size_t)N_NODES * 64);    // N+1
    int*   starts = degi + (N_NODES + 1);                  // N+1
    int*   cursor = starts + (N_NODES + 1);                // N
    int*   blockSums = cursor + N_NODES;                   // 512
    int*   blockOffs = blockSums + 512;                    // 512
    float* isq  = (float*)(blockOffs + 512);               // N
    float* npos = isq + N_NODES;                           // 1

    hipMemsetAsync(degi, 0, (N_NODES + 1) * sizeof(int), stream);
    hipMemsetAsync(npos, 0, sizeof(float), stream);
    hipMemsetAsync(out, 0, sizeof(float), stream);

    const int EB = (N_EDGES + 255) / 256;        // 12500
    const int SCB = (N_NODES + 1 + 255) / 256;   // 391 (covers 0..N)
    const int LB = (N_NODES + 3) / 4;            // 25000

    count_kernel<<<EB, 256, 0, stream>>>(col, degi);
    scan_blocks_kernel<<<SCB, 256, 0, stream>>>(degi, starts, blockSums);
    scan_sums_kernel<<<1, 512, 0, stream>>>(blockSums, blockOffs, SCB);
    finalize_kernel<<<SCB, 256, 0, stream>>>(starts, blockOffs, degi, cursor, isq, labels, npos);
    fill_kernel<<<EB, 256, 0, stream>>>(row, col, isq, cursor, edges);

    // layer 1 (K=32)
    linear_kernel<32><<<LB, 256, 0, stream>>>(x, W1, bufM);
    gather_kernel<<<LB, 256, 0, stream>>>(starts, edges, bufM, isq, b1, bufA);
    // layer 2 (K=64)
    linear_kernel<64><<<LB, 256, 0, stream>>>(bufA, W2, bufM);
    gather_kernel<<<LB, 256, 0, stream>>>(starts, edges, bufM, isq, b2, bufA);
    // layer 3 (K=64)
    linear_kernel<64><<<LB, 256, 0, stream>>>(bufA, W3, bufM);
    gather_kernel<<<LB, 256, 0, stream>>>(starts, edges, bufM, isq, b3, bufA);

    head_kernel<<<391, 256, 0, stream>>>(bufA, Wl1, bl1, Wl2, bl2, labels, npos, out);
}

// Round 3
// 676.292 us; speedup vs baseline: 12.0063x; 1.2795x over previous
//
#include <hip/hip_runtime.h>
#include <math.h>

#define N_NODES 100000
#define N_EDGES 3200000
#define NPB 256                              // nodes per bucket
#define NBUCK ((N_NODES + NPB - 1) / NPB)    // 391

// ---- pass A: bucket histogram (LDS-aggregated) ----
__global__ void bucket_hist_kernel(const int* __restrict__ col, int* __restrict__ bucketCnt) {
    __shared__ int h[NBUCK];
    for (int t = threadIdx.x; t < NBUCK; t += 256) h[t] = 0;
    __syncthreads();
    for (int e = blockIdx.x * 256 + threadIdx.x; e < N_EDGES; e += gridDim.x * 256)
        atomicAdd(&h[col[e] >> 8], 1);
    __syncthreads();
    for (int t = threadIdx.x; t < NBUCK; t += 256)
        if (h[t]) atomicAdd(&bucketCnt[t], h[t]);
}

// ---- pass B: scan bucket counts -> bucketOff; init bcursor ----
__global__ void bucket_scan_kernel(const int* __restrict__ bucketCnt, int* __restrict__ bucketOff,
                                   int* __restrict__ bcursor) {
    __shared__ int tmp[512];
    int tx = threadIdx.x;
    int v = (tx < NBUCK) ? bucketCnt[tx] : 0;
    tmp[tx] = v;
    __syncthreads();
    for (int off = 1; off < 512; off <<= 1) {
        int t = (tx >= off) ? tmp[tx - off] : 0;
        __syncthreads();
        if (tx >= off) tmp[tx] += t;
        __syncthreads();
    }
    if (tx < NBUCK) {
        int o = tmp[tx] - v;
        bucketOff[tx] = o;
        bcursor[tx] = o;
    }
}

// ---- pass C: bin edges by bucket (block-aggregated append, dense-ish writes) ----
// 512 threads, 4096 edges/block: rank in LDS hist, 1 global atomic per (block,bucket).
__global__ void bin_kernel(const int* __restrict__ row, const int* __restrict__ col,
                           int* __restrict__ bcursor, int2* __restrict__ tmpE) {
    __shared__ int hist[NBUCK];
    __shared__ int chunkOff[NBUCK];
    int tx = threadIdx.x;
    for (int t = tx; t < NBUCK; t += 512) hist[t] = 0;
    __syncthreads();
    int base = blockIdx.x * 4096;
    int myc[8], myr[8], myrank[8];
#pragma unroll 8
    for (int k = 0; k < 8; ++k) {
        int idx = base + k * 512 + tx;
        bool valid = idx < N_EDGES;
        int c = valid ? col[idx] : 0;
        int r = valid ? row[idx] : 0;
        myc[k] = c;
        myr[k] = r;
        myrank[k] = valid ? atomicAdd(&hist[c >> 8], 1) : 0;
    }
    __syncthreads();
    for (int t = tx; t < NBUCK; t += 512) {
        int hv = hist[t];
        chunkOff[t] = hv ? atomicAdd(&bcursor[t], hv) : 0;
    }
    __syncthreads();
#pragma unroll 8
    for (int k = 0; k < 8; ++k) {
        int idx = base + k * 512 + tx;
        if (idx < N_EDGES) {
            int pos = chunkOff[myc[k] >> 8] + myrank[k];
            tmpE[pos] = make_int2(myr[k], myc[k]);
        }
    }
}

// ---- pass D: per-bucket CSR build: starts, isq, edgeRow; + npos reduction ----
__global__ void csr_kernel(const int2* __restrict__ tmpE, const int* __restrict__ bucketOff,
                           const int* __restrict__ bucketCnt, int* __restrict__ starts,
                           int* __restrict__ edgeRow, float* __restrict__ isq,
                           const float* __restrict__ labels, float* __restrict__ npos) {
    __shared__ int scnt[NPB];
    __shared__ int sscan[NPB];
    __shared__ int scur[NPB];
    __shared__ float red[NPB];
    int b = blockIdx.x;
    int lo = b * NPB;
    int nn = N_NODES - lo;
    if (nn > NPB) nn = NPB;
    int base = bucketOff[b];
    int ecnt = bucketCnt[b];
    int tx = threadIdx.x;
    scnt[tx] = 0;
    __syncthreads();
    for (int t = tx; t < ecnt; t += NPB) atomicAdd(&scnt[tmpE[base + t].y - lo], 1);
    __syncthreads();
    int v = scnt[tx];
    sscan[tx] = v;
    __syncthreads();
    for (int off = 1; off < NPB; off <<= 1) {
        int t = (tx >= off) ? sscan[tx - off] : 0;
        __syncthreads();
        if (tx >= off) sscan[tx] += t;
        __syncthreads();
    }
    int excl = sscan[tx] - v;
    scur[tx] = excl;
    float lab = 0.0f;
    if (tx < nn) {
        starts[lo + tx] = base + excl;
        isq[lo + tx] = rsqrtf((float)v + 1.0f);
        lab = labels[lo + tx];
    }
    if (b == NBUCK - 1 && tx == 0) starts[N_NODES] = N_EDGES;
    red[tx] = lab;
    __syncthreads();
    for (int s = NPB / 2; s > 0; s >>= 1) {
        if (tx < s) red[tx] += red[tx + s];
        __syncthreads();
    }
    if (tx == 0) atomicAdd(npos, red[0]);
    for (int t = tx; t < ecnt; t += NPB) {
        int2 rc = tmpE[base + t];
        int p = atomicAdd(&scur[rc.y - lo], 1);
        edgeRow[base + p] = rc.x;
    }
}

// ---- m = in @ W ; weights staged in LDS; 4 nodes/block ----
template <int K>
__global__ void linear_kernel(const float* __restrict__ in, const float* __restrict__ W,
                              float* __restrict__ m) {
    __shared__ float sW[K * 64];
    for (int t = threadIdx.x; t < K * 64; t += 256) sW[t] = W[t];
    __syncthreads();
    int node = blockIdx.x * 4 + (threadIdx.x >> 6);
    int f = threadIdx.x & 63;
    if (node >= N_NODES) return;
    const float* inr = in + (size_t)node * K;
    float acc = 0.0f;
#pragma unroll
    for (int k = 0; k < K; ++k) acc = fmaf(inr[k], sW[k * 64 + f], acc);
    m[(size_t)node * 64 + f] = acc;
}

// ---- gather: h[i] = relu( sum m[row_e]*isq[row_e]*isq[i] + m[i]*isq[i]^2 + b ) ----
__global__ void gather_kernel(const int* __restrict__ starts, const int* __restrict__ edgeRow,
                              const float* __restrict__ m, const float* __restrict__ isq,
                              const float* __restrict__ bias, float* __restrict__ h) {
    int node = blockIdx.x * 4 + (threadIdx.x >> 6);
    int lane = threadIdx.x & 63;
    if (node >= N_NODES) return;
    int s = starts[node];
    int e = starts[node + 1];
    float si = isq[node];
    float acc = m[(size_t)node * 64 + lane] * si * si;  // self-loop term
    float acc2 = 0.0f;
    while (s < e) {
        int cnt = e - s;
        if (cnt > 64) cnt = 64;
        int rr = 0;
        float nv = 0.0f;
        if (lane < cnt) {
            rr = edgeRow[s + lane];
            nv = isq[rr] * si;
        }
        int j = 0;
        for (; j + 2 <= cnt; j += 2) {
            int r0 = __shfl(rr, j);
            int r1 = __shfl(rr, j + 1);
            float n0 = __shfl(nv, j);
            float n1 = __shfl(nv, j + 1);
            acc = fmaf(m[(size_t)r0 * 64 + lane], n0, acc);
            acc2 = fmaf(m[(size_t)r1 * 64 + lane], n1, acc2);
        }
        if (j < cnt) {
            int r0 = __shfl(rr, j);
            float n0 = __shfl(nv, j);
            acc = fmaf(m[(size_t)r0 * 64 + lane], n0, acc);
        }
        s += cnt;
    }
    float vv = acc + acc2 + bias[lane];
    h[(size_t)node * 64 + lane] = vv > 0.0f ? vv : 0.0f;
}

// ---- head: relu(h@Wl1+bl1)@Wl2+bl2 -> sigmoid -> p; weighted BCE -> loss ----
__global__ void head_kernel(const float* __restrict__ h, const float* __restrict__ Wl1,
                            const float* __restrict__ bl1, const float* __restrict__ Wl2,
                            const float* __restrict__ bl2, const float* __restrict__ labels,
                            const float* __restrict__ npos, float* __restrict__ out) {
    __shared__ float sW1[64 * 8];
    __shared__ float sb1[8];
    __shared__ float sW2[8];
    for (int t = threadIdx.x; t < 512; t += 256) sW1[t] = Wl1[t];
    if (threadIdx.x < 8) {
        sb1[threadIdx.x] = bl1[threadIdx.x];
        sW2[threadIdx.x] = Wl2[threadIdx.x];
    }
    __syncthreads();
    int i = blockIdx.x * 256 + threadIdx.x;
    float contrib = 0.0f;
    if (i < N_NODES) {
        const float* hr = h + (size_t)i * 64;
        float a[8];
#pragma unroll
        for (int j = 0; j < 8; ++j) a[j] = sb1[j];
        for (int k = 0; k < 64; ++k) {
            float hv = hr[k];
#pragma unroll
            for (int j = 0; j < 8; ++j) a[j] = fmaf(hv, sW1[k * 8 + j], a[j]);
        }
        float z = bl2[0];
#pragma unroll
        for (int j = 0; j < 8; ++j) {
            float r = a[j] > 0.0f ? a[j] : 0.0f;
            z = fmaf(r, sW2[j], z);
        }
        float p = 1.0f / (1.0f + expf(-z));
        out[1 + i] = p;
        float y = labels[i];
        float np = *npos;
        float fn = (float)N_NODES;
        float wpos = fn / (2.0f * np);
        float wneg = fn / (2.0f * (fn - np));
        float w = y * wpos + (1.0f - y) * wneg;
        float lse = log1pf(expf(-fabsf(z)));
        float ls_pos = fminf(z, 0.0f) - lse;
        float ls_neg = fminf(-z, 0.0f) - lse;
        float bce = -(y * ls_pos + (1.0f - y) * ls_neg);
        contrib = w * bce / fn;
    }
    __shared__ float red[256];
    red[threadIdx.x] = contrib;
    __syncthreads();
    for (int s = 128; s > 0; s >>= 1) {
        if (threadIdx.x < s) red[threadIdx.x] += red[threadIdx.x + s];
        __syncthreads();
    }
    if (threadIdx.x == 0) atomicAdd(out, red[0]);
}

extern "C" void kernel_launch(void* const* d_in, const int* in_sizes, int n_in,
                              void* d_out, int out_size, void* d_ws, size_t ws_size,
                              hipStream_t stream) {
    const float* x      = (const float*)d_in[0];
    const int*   ei     = (const int*)d_in[1];
    const float* labels = (const float*)d_in[2];
    const float* W1  = (const float*)d_in[3];
    const float* b1  = (const float*)d_in[4];
    const float* W2  = (const float*)d_in[5];
    const float* b2  = (const float*)d_in[6];
    const float* W3  = (const float*)d_in[7];
    const float* b3  = (const float*)d_in[8];
    const float* Wl1 = (const float*)d_in[9];
    const float* bl1 = (const float*)d_in[10];
    const float* Wl2 = (const float*)d_in[11];
    const float* bl2 = (const float*)d_in[12];

    const int* row = ei;            // edge_index[0]
    const int* col = ei + N_EDGES;  // edge_index[1]
    float* out = (float*)d_out;

    // ---- workspace layout ----
    char* w = (char*)d_ws;
    int2*  tmpE    = (int2*)w;                                  // E * 8B
    int*   edgeRow = (int*)(w + (size_t)N_EDGES * 8);           // E
    float* bufM    = (float*)(edgeRow + N_EDGES);               // N*64
    float* bufA    = bufM + (size_t)N_NODES * 64;               // N*64
    int*   starts  = (int*)(bufA + (size_t)N_NODES * 64);       // N+1
    int*   bucketCnt = starts + (N_NODES + 1);                  // NBUCK
    int*   bucketOff = bucketCnt + NBUCK;                       // NBUCK
    int*   bcursor   = bucketOff + NBUCK;                       // NBUCK
    float* isq  = (float*)(bcursor + NBUCK);                    // N
    float* npos = isq + N_NODES;                                // 1

    hipMemsetAsync(bucketCnt, 0, NBUCK * sizeof(int), stream);
    hipMemsetAsync(npos, 0, sizeof(float), stream);
    hipMemsetAsync(out, 0, sizeof(float), stream);

    const int LB = (N_NODES + 3) / 4;            // 25000
    const int BB = (N_EDGES + 4095) / 4096;      // 782

    bucket_hist_kernel<<<1024, 256, 0, stream>>>(col, bucketCnt);
    bucket_scan_kernel<<<1, 512, 0, stream>>>(bucketCnt, bucketOff, bcursor);
    bin_kernel<<<BB, 512, 0, stream>>>(row, col, bcursor, tmpE);
    csr_kernel<<<NBUCK, NPB, 0, stream>>>(tmpE, bucketOff, bucketCnt, starts, edgeRow, isq,
                                          labels, npos);

    // layer 1 (K=32)
    linear_kernel<32><<<LB, 256, 0, stream>>>(x, W1, bufM);
    gather_kernel<<<LB, 256, 0, stream>>>(starts, edgeRow, bufM, isq, b1, bufA);
    // layer 2 (K=64)
    linear_kernel<64><<<LB, 256, 0, stream>>>(bufA, W2, bufM);
    gather_kernel<<<LB, 256, 0, stream>>>(starts, edgeRow, bufM, isq, b2, bufA);
    // layer 3 (K=64)
    linear_kernel<64><<<LB, 256, 0, stream>>>(bufA, W3, bufM);
    gather_kernel<<<LB, 256, 0, stream>>>(starts, edgeRow, bufM, isq, b3, bufA);

    head_kernel<<<391, 256, 0, stream>>>(bufA, Wl1, bl1, Wl2, bl2, labels, npos, out);
}

// Round 4
// 570.007 us; speedup vs baseline: 14.2450x; 1.1865x over previous
//
#include <hip/hip_runtime.h>
#include <math.h>

#define N_NODES 100000
#define N_EDGES 3200000
#define NPB 256                              // nodes per bucket
#define NBUCK ((N_NODES + NPB - 1) / NPB)    // 391

typedef unsigned short ushort_t;

static __device__ __forceinline__ float bf2f(ushort_t u) {
    return __uint_as_float(((unsigned int)u) << 16);
}
static __device__ __forceinline__ ushort_t f2bf(float f) {
    unsigned int x = __float_as_uint(f);
    unsigned int lsb = (x >> 16) & 1u;
    x += 0x7fffu + lsb;  // round-to-nearest-even
    return (ushort_t)(x >> 16);
}

// ---- pass A: bucket histogram (LDS-aggregated) ----
__global__ void bucket_hist_kernel(const int* __restrict__ col, int* __restrict__ bucketCnt) {
    __shared__ int h[NBUCK];
    for (int t = threadIdx.x; t < NBUCK; t += 256) h[t] = 0;
    __syncthreads();
    for (int e = blockIdx.x * 256 + threadIdx.x; e < N_EDGES; e += gridDim.x * 256)
        atomicAdd(&h[col[e] >> 8], 1);
    __syncthreads();
    for (int t = threadIdx.x; t < NBUCK; t += 256)
        if (h[t]) atomicAdd(&bucketCnt[t], h[t]);
}

// ---- pass B: scan bucket counts -> bucketOff; init bcursor ----
__global__ void bucket_scan_kernel(const int* __restrict__ bucketCnt, int* __restrict__ bucketOff,
                                   int* __restrict__ bcursor) {
    __shared__ int tmp[512];
    int tx = threadIdx.x;
    int v = (tx < NBUCK) ? bucketCnt[tx] : 0;
    tmp[tx] = v;
    __syncthreads();
    for (int off = 1; off < 512; off <<= 1) {
        int t = (tx >= off) ? tmp[tx - off] : 0;
        __syncthreads();
        if (tx >= off) tmp[tx] += t;
        __syncthreads();
    }
    if (tx < NBUCK) {
        int o = tmp[tx] - v;
        bucketOff[tx] = o;
        bcursor[tx] = o;
    }
}

// ---- pass C: bin edges by bucket (block-aggregated append) ----
__global__ void bin_kernel(const int* __restrict__ row, const int* __restrict__ col,
                           int* __restrict__ bcursor, int2* __restrict__ tmpE) {
    __shared__ int hist[NBUCK];
    __shared__ int chunkOff[NBUCK];
    int tx = threadIdx.x;
    for (int t = tx; t < NBUCK; t += 512) hist[t] = 0;
    __syncthreads();
    int base = blockIdx.x * 4096;
    int myc[8], myr[8], myrank[8];
#pragma unroll 8
    for (int k = 0; k < 8; ++k) {
        int idx = base + k * 512 + tx;
        bool valid = idx < N_EDGES;
        int c = valid ? col[idx] : 0;
        int r = valid ? row[idx] : 0;
        myc[k] = c;
        myr[k] = r;
        myrank[k] = valid ? atomicAdd(&hist[c >> 8], 1) : 0;
    }
    __syncthreads();
    for (int t = tx; t < NBUCK; t += 512) {
        int hv = hist[t];
        chunkOff[t] = hv ? atomicAdd(&bcursor[t], hv) : 0;
    }
    __syncthreads();
#pragma unroll 8
    for (int k = 0; k < 8; ++k) {
        int idx = base + k * 512 + tx;
        if (idx < N_EDGES) {
            int pos = chunkOff[myc[k] >> 8] + myrank[k];
            tmpE[pos] = make_int2(myr[k], myc[k]);
        }
    }
}

// ---- pass D: per-bucket CSR: starts, isq, edgeRow; + npos reduction ----
__global__ void csr_kernel(const int2* __restrict__ tmpE, const int* __restrict__ bucketOff,
                           const int* __restrict__ bucketCnt, int* __restrict__ starts,
                           int* __restrict__ edgeRow, float* __restrict__ isq,
                           const float* __restrict__ labels, float* __restrict__ npos) {
    __shared__ int scnt[NPB];
    __shared__ int sscan[NPB];
    __shared__ int scur[NPB];
    __shared__ float red[NPB];
    int b = blockIdx.x;
    int lo = b * NPB;
    int nn = N_NODES - lo;
    if (nn > NPB) nn = NPB;
    int base = bucketOff[b];
    int ecnt = bucketCnt[b];
    int tx = threadIdx.x;
    scnt[tx] = 0;
    __syncthreads();
    for (int t = tx; t < ecnt; t += NPB) atomicAdd(&scnt[tmpE[base + t].y - lo], 1);
    __syncthreads();
    int v = scnt[tx];
    sscan[tx] = v;
    __syncthreads();
    for (int off = 1; off < NPB; off <<= 1) {
        int t = (tx >= off) ? sscan[tx - off] : 0;
        __syncthreads();
        if (tx >= off) sscan[tx] += t;
        __syncthreads();
    }
    int excl = sscan[tx] - v;
    scur[tx] = excl;
    float lab = 0.0f;
    if (tx < nn) {
        starts[lo + tx] = base + excl;
        isq[lo + tx] = rsqrtf((float)v + 1.0f);
        lab = labels[lo + tx];
    }
    if (b == NBUCK - 1 && tx == 0) starts[N_NODES] = N_EDGES;
    red[tx] = lab;
    __syncthreads();
    for (int s = NPB / 2; s > 0; s >>= 1) {
        if (tx < s) red[tx] += red[tx + s];
        __syncthreads();
    }
    if (tx == 0) atomicAdd(npos, red[0]);
    for (int t = tx; t < ecnt; t += NPB) {
        int2 rc = tmpE[base + t];
        int p = atomicAdd(&scur[rc.y - lo], 1);
        edgeRow[base + p] = rc.x;
    }
}

// ---- x (fp32 N*32) -> bf16 table ----
__global__ void xcast_kernel(const float* __restrict__ x, ushort_t* __restrict__ xbf) {
    int i = blockIdx.x * 256 + threadIdx.x;  // group of 4
    if (i < (N_NODES * 32) / 4) {
        float4 v = ((const float4*)x)[i];
        ushort4 o;
        o.x = f2bf(v.x); o.y = f2bf(v.y); o.z = f2bf(v.z); o.w = f2bf(v.w);
        ((ushort4*)xbf)[i] = o;
    }
}

// ---- layer 1 fused: agg(x)[32] -> @W[32x64]+b -> relu -> bf16 h ----
// one wave per node; lane = (feat | edge-parity); 2 edges per iteration
__global__ void fused32_kernel(const int* __restrict__ starts, const int* __restrict__ edgeRow,
                               const ushort_t* __restrict__ xbf, const float* __restrict__ isq,
                               const float* __restrict__ W, const float* __restrict__ bias,
                               ushort_t* __restrict__ hout) {
    __shared__ float sW[32 * 64];
    __shared__ float sAgg[4][32];
    for (int t = threadIdx.x; t < 32 * 64; t += 256) sW[t] = W[t];
    int node = blockIdx.x * 4 + (threadIdx.x >> 6);  // N divisible by 4: no guard
    int lane = threadIdx.x & 63;
    int f = lane & 31, half = lane >> 5;
    int w = threadIdx.x >> 6;
    int s = starts[node], e = starts[node + 1];
    float si = isq[node];
    float acc = 0.0f;
    while (s < e) {
        int cnt = e - s;
        if (cnt > 64) cnt = 64;
        int rr = 0;
        float nv = 0.0f;
        if (lane < cnt) {
            rr = edgeRow[s + lane];
            nv = isq[rr] * si;
        }
        for (int j = 0; j < cnt; j += 2) {
            int jj = j + half;                 // lanes with jj>=cnt see rr=0,nv=0
            int r = __shfl(rr, jj);
            float n = __shfl(nv, jj);
            acc = fmaf(bf2f(xbf[(size_t)r * 32 + f]), n, acc);
        }
        s += cnt;
    }
    float other = __shfl(acc, f + 32);
    if (half == 0) {
        acc += other;
        acc = fmaf(bf2f(xbf[(size_t)node * 32 + f]), si * si, acc);  // self-loop
        sAgg[w][f] = acc;
    }
    __syncthreads();
    float o = bias[lane];
#pragma unroll
    for (int k = 0; k < 32; ++k) o = fmaf(sAgg[w][k], sW[k * 64 + lane], o);
    o = o > 0.0f ? o : 0.0f;
    hout[(size_t)node * 64 + lane] = f2bf(o);
}

// ---- layers 2/3 fused: agg(h)[64] -> @W[64x64]+b -> relu -> bf16 h ----
__global__ void fused64_kernel(const int* __restrict__ starts, const int* __restrict__ edgeRow,
                               const ushort_t* __restrict__ hin, const float* __restrict__ isq,
                               const float* __restrict__ W, const float* __restrict__ bias,
                               ushort_t* __restrict__ hout) {
    __shared__ float sW[64 * 64];
    __shared__ float sAgg[4][64];
    for (int t = threadIdx.x; t < 64 * 64; t += 256) sW[t] = W[t];
    int node = blockIdx.x * 4 + (threadIdx.x >> 6);
    int lane = threadIdx.x & 63;
    int w = threadIdx.x >> 6;
    int s = starts[node], e = starts[node + 1];
    float si = isq[node];
    float acc = bf2f(hin[(size_t)node * 64 + lane]) * si * si;  // self-loop
    float acc2 = 0.0f;
    while (s < e) {
        int cnt = e - s;
        if (cnt > 64) cnt = 64;
        int rr = 0;
        float nv = 0.0f;
        if (lane < cnt) {
            rr = edgeRow[s + lane];
            nv = isq[rr] * si;
        }
        int j = 0;
        for (; j + 2 <= cnt; j += 2) {
            int r0 = __shfl(rr, j), r1 = __shfl(rr, j + 1);
            float n0 = __shfl(nv, j), n1 = __shfl(nv, j + 1);
            acc = fmaf(bf2f(hin[(size_t)r0 * 64 + lane]), n0, acc);
            acc2 = fmaf(bf2f(hin[(size_t)r1 * 64 + lane]), n1, acc2);
        }
        if (j < cnt) {
            int r0 = __shfl(rr, j);
            float n0 = __shfl(nv, j);
            acc = fmaf(bf2f(hin[(size_t)r0 * 64 + lane]), n0, acc);
        }
        s += cnt;
    }
    sAgg[w][lane] = acc + acc2;
    __syncthreads();
    float o = bias[lane];
#pragma unroll
    for (int k = 0; k < 64; ++k) o = fmaf(sAgg[w][k], sW[k * 64 + lane], o);
    o = o > 0.0f ? o : 0.0f;
    hout[(size_t)node * 64 + lane] = f2bf(o);
}

// ---- head: relu(h@Wl1+bl1)@Wl2+bl2 -> sigmoid -> p; weighted BCE -> loss ----
__global__ void head_kernel(const ushort_t* __restrict__ h, const float* __restrict__ Wl1,
                            const float* __restrict__ bl1, const float* __restrict__ Wl2,
                            const float* __restrict__ bl2, const float* __restrict__ labels,
                            const float* __restrict__ npos, float* __restrict__ out) {
    __shared__ float sW1[64 * 8];
    __shared__ float sb1[8];
    __shared__ float sW2[8];
    for (int t = threadIdx.x; t < 512; t += 256) sW1[t] = Wl1[t];
    if (threadIdx.x < 8) {
        sb1[threadIdx.x] = bl1[threadIdx.x];
        sW2[threadIdx.x] = Wl2[threadIdx.x];
    }
    __syncthreads();
    int i = blockIdx.x * 256 + threadIdx.x;
    float contrib = 0.0f;
    if (i < N_NODES) {
        const ushort4* hr4 = (const ushort4*)(h + (size_t)i * 64);
        float a[8];
#pragma unroll
        for (int j = 0; j < 8; ++j) a[j] = sb1[j];
#pragma unroll
        for (int kb = 0; kb < 16; ++kb) {
            ushort4 v4 = hr4[kb];
            float h0 = bf2f(v4.x), h1 = bf2f(v4.y), h2 = bf2f(v4.z), h3 = bf2f(v4.w);
#pragma unroll
            for (int j = 0; j < 8; ++j) {
                a[j] = fmaf(h0, sW1[(kb * 4 + 0) * 8 + j], a[j]);
                a[j] = fmaf(h1, sW1[(kb * 4 + 1) * 8 + j], a[j]);
                a[j] = fmaf(h2, sW1[(kb * 4 + 2) * 8 + j], a[j]);
                a[j] = fmaf(h3, sW1[(kb * 4 + 3) * 8 + j], a[j]);
            }
        }
        float z = bl2[0];
#pragma unroll
        for (int j = 0; j < 8; ++j) {
            float r = a[j] > 0.0f ? a[j] : 0.0f;
            z = fmaf(r, sW2[j], z);
        }
        float p = 1.0f / (1.0f + expf(-z));
        out[1 + i] = p;
        float y = labels[i];
        float np = *npos;
        float fn = (float)N_NODES;
        float wpos = fn / (2.0f * np);
        float wneg = fn / (2.0f * (fn - np));
        float wgt = y * wpos + (1.0f - y) * wneg;
        float lse = log1pf(expf(-fabsf(z)));
        float ls_pos = fminf(z, 0.0f) - lse;
        float ls_neg = fminf(-z, 0.0f) - lse;
        float bce = -(y * ls_pos + (1.0f - y) * ls_neg);
        contrib = wgt * bce / fn;
    }
    __shared__ float red[256];
    red[threadIdx.x] = contrib;
    __syncthreads();
    for (int s = 128; s > 0; s >>= 1) {
        if (threadIdx.x < s) red[threadIdx.x] += red[threadIdx.x + s];
        __syncthreads();
    }
    if (threadIdx.x == 0) atomicAdd(out, red[0]);
}

extern "C" void kernel_launch(void* const* d_in, const int* in_sizes, int n_in,
                              void* d_out, int out_size, void* d_ws, size_t ws_size,
                              hipStream_t stream) {
    const float* x      = (const float*)d_in[0];
    const int*   ei     = (const int*)d_in[1];
    const float* labels = (const float*)d_in[2];
    const float* W1  = (const float*)d_in[3];
    const float* b1  = (const float*)d_in[4];
    const float* W2  = (const float*)d_in[5];
    const float* b2  = (const float*)d_in[6];
    const float* W3  = (const float*)d_in[7];
    const float* b3  = (const float*)d_in[8];
    const float* Wl1 = (const float*)d_in[9];
    const float* bl1 = (const float*)d_in[10];
    const float* Wl2 = (const float*)d_in[11];
    const float* bl2 = (const float*)d_in[12];

    const int* row = ei;            // edge_index[0]
    const int* col = ei + N_EDGES;  // edge_index[1]
    float* out = (float*)d_out;

    // ---- workspace layout ----
    char* w = (char*)d_ws;
    int2*     tmpE    = (int2*)w;                               // E*8B
    int*      edgeRow = (int*)(w + (size_t)N_EDGES * 8);        // E*4B
    ushort_t* xbf     = (ushort_t*)(edgeRow + N_EDGES);         // N*32*2B
    ushort_t* hbfA    = xbf + (size_t)N_NODES * 32;             // N*64*2B
    ushort_t* hbfB    = hbfA + (size_t)N_NODES * 64;            // N*64*2B
    int*      starts  = (int*)(hbfB + (size_t)N_NODES * 64);    // N+1
    int*      bucketCnt = starts + (N_NODES + 1);               // NBUCK
    int*      bucketOff = bucketCnt + NBUCK;                    // NBUCK
    int*      bcursor   = bucketOff + NBUCK;                    // NBUCK
    float*    isq  = (float*)(bcursor + NBUCK);                 // N
    float*    npos = isq + N_NODES;                             // 1

    hipMemsetAsync(bucketCnt, 0, NBUCK * sizeof(int), stream);
    hipMemsetAsync(npos, 0, sizeof(float), stream);
    hipMemsetAsync(out, 0, sizeof(float), stream);

    const int LB = N_NODES / 4;              // 25000 (N divisible by 4)
    const int BB = (N_EDGES + 4095) / 4096;  // 782
    const int XB = (N_NODES * 32 / 4 + 255) / 256;

    bucket_hist_kernel<<<1024, 256, 0, stream>>>(col, bucketCnt);
    bucket_scan_kernel<<<1, 512, 0, stream>>>(bucketCnt, bucketOff, bcursor);
    bin_kernel<<<BB, 512, 0, stream>>>(row, col, bcursor, tmpE);
    csr_kernel<<<NBUCK, NPB, 0, stream>>>(tmpE, bucketOff, bucketCnt, starts, edgeRow, isq,
                                          labels, npos);
    xcast_kernel<<<XB, 256, 0, stream>>>(x, xbf);

    fused32_kernel<<<LB, 256, 0, stream>>>(starts, edgeRow, xbf, isq, W1, b1, hbfA);
    fused64_kernel<<<LB, 256, 0, stream>>>(starts, edgeRow, hbfA, isq, W2, b2, hbfB);
    fused64_kernel<<<LB, 256, 0, stream>>>(starts, edgeRow, hbfB, isq, W3, b3, hbfA);

    head_kernel<<<(N_NODES + 255) / 256, 256, 0, stream>>>(hbfA, Wl1, bl1, Wl2, bl2, labels,
                                                           npos, out);
}